// Round 4
// baseline (337.186 us; speedup 1.0000x reference)
//
#include <hip/hip_runtime.h>
#include <hip/hip_bf16.h>

#define H_ 64
#define W_ 2048
#define HWsz (H_*W_)
#define CIN 64
#define CTOT 68
#define COUT 64

typedef float  f32x2  __attribute__((ext_vector_type(2)));
typedef float  f32x4  __attribute__((ext_vector_type(4)));
typedef float  f32x16 __attribute__((ext_vector_type(16)));
typedef short  s16x8  __attribute__((ext_vector_type(8)));

__device__ __forceinline__ unsigned short f2bf(float f) {
    unsigned u = __builtin_bit_cast(unsigned, f);
    unsigned r = u + 0x7fffu + ((u >> 16) & 1u);   // RNE; inputs finite
    return (unsigned short)(r >> 16);
}

__device__ __forceinline__ unsigned pack2bf(float a, float b) {
    __hip_bfloat162 h = __float22bfloat162_rn(float2{a, b});   // v_cvt_pk_bf16_f32
    unsigned u;
    __builtin_memcpy(&u, &h, 4);
    return u;
}

// ---------------- prep: Wagg -> bf16 MFMA A-fragments; fold BN1 ----------------
// BwS idx lane l: o = nt*32+(l&31), ch = ks*16+(l>>5)*8+j  (A[m=o][k=ch] layout)
__global__ __launch_bounds__(256) void prep_bw(
    const float* __restrict__ Wagg,
    const float* __restrict__ W1, const float* __restrict__ g1,
    const float* __restrict__ b1, const float* __restrict__ m1,
    const float* __restrict__ v1, const float* __restrict__ W2,
    unsigned short* __restrict__ BwS, float* __restrict__ Wfold)
{
    int tid = threadIdx.x;
    if (blockIdx.x == 0) {
        if (tid < 64) {
            float s1 = g1[tid] * rsqrtf(v1[tid] + 1e-5f);
#pragma unroll
            for (int m = 0; m < 4; ++m) Wfold[tid*8 + m] = W1[tid*4 + m] * s1;
            Wfold[tid*8 + 4] = b1[tid] - m1[tid]*s1;
            Wfold[tid*8 + 5] = W2[tid];
            Wfold[tid*8 + 6] = 0.f;
            Wfold[tid*8 + 7] = 0.f;
        }
        __syncthreads();
        if (tid == 0) {
            float s = 0.f;
            for (int c = 0; c < 64; ++c) s += fmaxf(Wfold[c*8 + 4], 0.f) * Wfold[c*8 + 5];
            Wfold[512] = s;
        }
    }
    int idx = blockIdx.x * 256 + tid;
    if (idx < 4608) {
        int lane = idx & 63;
        int rest = idx >> 6;
        int nt = rest & 1;
        int ks = (rest >> 1) & 3;
        int k9 = rest >> 3;
        int o  = nt*32 + (lane & 31);
        int ch = ks*16 + (lane >> 5)*8;
        const float* src = Wagg + (size_t)o*(9*CIN) + k9*64 + ch;
        s16x8 v8;
#pragma unroll
        for (int j = 0; j < 8; ++j) v8[j] = (short)f2bf(src[j]);
        *(s16x8*)(BwS + (size_t)idx*8) = v8;
    }
}

// ---------------- sw_k: logit MLP + softmax -> sws[b][h][9][W] (fp32) ----------------
__global__ __launch_bounds__(512, 8) void sw_k(
    const float* __restrict__ x, const int* __restrict__ mask,
    const float* __restrict__ Wfold, const float* __restrict__ b2p,
    float* __restrict__ sws)
{
    __shared__ float sw[2][9][64];

    const int tid = threadIdx.x;
    const int bx = blockIdx.x, by = blockIdx.y;
    const int b = by >> 5, h0 = (by & 31) << 1;
    const int w0 = bx << 6;
    const int lane = tid & 63, wv = tid >> 6;

    const float* xp = x + (size_t)b*CTOT*HWsz;         // pos channels 0..3
    const int*   mk = mask + (size_t)b*HWsz;

    const int px = lane, gw = w0 + px;
    const int rowq = wv >> 2, tg = wv & 3;
    const int h = h0 + rowq;
    const int ka = 2*tg + (tg >> 1);        // tg 0..3 -> taps {0,1},{2,3},{5,6},{7,8}

    float pc[4];
#pragma unroll
    for (int ch = 0; ch < 4; ++ch) pc[ch] = xp[(size_t)ch*HWsz + (size_t)h*W_ + gw];

    f32x2 dd[4]; f32x2 mu;
#pragma unroll
    for (int i = 0; i < 2; ++i) {
        int k = ka + i;
        int r = k/3 - 1, d = k%3 - 1;
        int ih = h + r, iw = gw + d;
        bool ok = ((unsigned)ih < (unsigned)H_) && ((unsigned)iw < (unsigned)W_);
        int ihc = min(max(ih, 0), H_-1);
        int iwc = min(max(iw, 0), W_-1);
        mu[i] = ok ? (float)mk[(size_t)ihc*W_ + iwc] : 0.f;
#pragma unroll
        for (int ch = 0; ch < 4; ++ch) {
            float p = xp[(size_t)ch*HWsz + (size_t)ihc*W_ + iwc];
            dd[ch][i] = (ok ? p : 0.f) - pc[ch];   // reference zero-pads pn
        }
    }

    const f32x4* Wf4 = (const f32x4*)Wfold;
    const f32x2 z2 = {0.f, 0.f};
    f32x2 lg = z2;
#pragma unroll 8
    for (int c = 0; c < CIN; ++c) {
        f32x4 wa = Wf4[2*c];        // wave-uniform s_load
        f32x4 wb = Wf4[2*c + 1];
        f32x2 v = {wb[0], wb[0]};
        v = dd[0]*wa[0] + v;          // packed f32x2 fma
        v = dd[1]*wa[1] + v;
        v = dd[2]*wa[2] + v;
        v = dd[3]*wa[3] + v;
        v = __builtin_elementwise_max(v, z2);
        lg = v*wb[1] + lg;
    }
    float b2v = b2p[0];
    sw[rowq][ka    ][px] = (lg[0] + b2v) * mu[0];
    sw[rowq][ka + 1][px] = (lg[1] + b2v) * mu[1];
    __syncthreads();

    // softmax over 9 taps (128 threads) -> global sws
    if (tid < 128) {
        int rq = tid >> 6, p2 = tid & 63;
        float mu4 = (float)mk[(size_t)(h0 + rq)*W_ + w0 + p2];
        float lgv[9];
#pragma unroll
        for (int k = 0; k < 9; ++k) if (k != 4) lgv[k] = sw[rq][k][p2];
        lgv[4] = (Wfold[512] + b2v) * mu4;
        float mx = -1e30f;
#pragma unroll
        for (int k = 0; k < 9; ++k) mx = fmaxf(mx, lgv[k]);
        float s = 0.f, e[9];
#pragma unroll
        for (int k = 0; k < 9; ++k) { e[k] = __expf(lgv[k] - mx); s += e[k]; }
        float inv = 1.f / s;
        float* dst = sws + ((size_t)(b*H_ + h0 + rq)*9)*W_ + w0 + p2;
#pragma unroll
        for (int k = 0; k < 9; ++k) dst[(size_t)k*W_] = e[k] * inv;
    }
}

// ---------------- agg_k: progressive staging + pipelined weighted MFMA ----------------
// Block 256 thr (4 waves), tile = 2 rows x 64 px x 64 out.
// bar1 after rows 0-1; k9 0-2 overlaps rows 2-3 loads; bar2; k9 3-8 with
// distance-1 BwS (aw) prefetch. Softmax weights staged to LDS (frees VGPRs).
__global__ __launch_bounds__(256, 4) void agg_k(
    const float* __restrict__ x, const float* __restrict__ sws,
    const unsigned short* __restrict__ BwS,
    const float* __restrict__ g2, const float* __restrict__ bb2,
    const float* __restrict__ m2, const float* __restrict__ v2,
    float* __restrict__ out)
{
    __shared__ __align__(16) unsigned short fe[4][8][66][8];   // 33,792 B
    __shared__ __align__(16) float swl[2][9][64];              //  4,608 B
    __shared__ __align__(16) float sbn[2][64];                 //    512 B

    const int tid = threadIdx.x;
    const int bx = blockIdx.x, by = blockIdx.y;
    const int b = by >> 5, h0 = (by & 31) << 1;
    const int w0 = bx << 6;
    const int lane = tid & 63, wv = tid >> 6;

    const float* xf = x + ((size_t)b*CTOT + 4)*HWsz;   // feat channels

    // --- phase-1 staging: fe rows 0-1 (tasks u = it*4+wv, r = u>>3 in {0,1}) ---
#pragma unroll
    for (int it = 0; it < 4; ++it) {
        int u = it*4 + wv;                  // wave-uniform
        int g = u & 7, r = u >> 3;
        int gr = h0 - 1 + r;
        uint4 q = {0u, 0u, 0u, 0u};
        if ((unsigned)gr < (unsigned)H_) {
            const float* src = xf + (size_t)(g*8)*HWsz + (size_t)gr*W_ + w0 + lane;
            float v[8];
#pragma unroll
            for (int j = 0; j < 8; ++j) v[j] = src[(size_t)j*HWsz];
            q.x = pack2bf(v[0], v[1]); q.y = pack2bf(v[2], v[3]);
            q.z = pack2bf(v[4], v[5]); q.w = pack2bf(v[6], v[7]);
        }
        *(uint4*)&fe[r][g][1 + lane][0] = q;
    }
    // halo rows 0-1: tid<32 (c2 x 8g x 2r)
    if (tid < 32) {
        int c2 = tid & 1, g = (tid >> 1) & 7, r = (tid >> 4) & 1;
        int gr = h0 - 1 + r, gc = w0 - 1 + c2*65;
        uint4 q = {0u, 0u, 0u, 0u};
        if (((unsigned)gr < (unsigned)H_) && ((unsigned)gc < (unsigned)W_)) {
            const float* src = xf + (size_t)(g*8)*HWsz + (size_t)gr*W_ + gc;
            float v[8];
#pragma unroll
            for (int j = 0; j < 8; ++j) v[j] = src[(size_t)j*HWsz];
            q.x = pack2bf(v[0], v[1]); q.y = pack2bf(v[2], v[3]);
            q.z = pack2bf(v[4], v[5]); q.w = pack2bf(v[6], v[7]);
        }
        *(uint4*)&fe[r][g][c2*65][0] = q;
    }
    // BN2 table: tid in [32,96)
    if (tid >= 32 && tid < 96) {
        int o = tid - 32;
        float sc = g2[o] * rsqrtf(v2[o] + 1e-5f);
        sbn[0][o] = sc;
        sbn[1][o] = bb2[o] - m2[o]*sc;
    }
    // softmax weights -> LDS: tid in [128,256)
    if (tid >= 128) {
        int idx = tid - 128;
        int rq = idx >> 6, p2 = idx & 63;
        const float* sp = sws + ((size_t)(b*H_ + h0 + rq)*9)*W_ + w0 + p2;
        float v[9];
#pragma unroll
        for (int k = 0; k < 9; ++k) v[k] = sp[(size_t)k*W_];
#pragma unroll
        for (int k = 0; k < 9; ++k) swl[rq][k][p2] = v[k];
    }
    __syncthreads();

    // --- issue rows 2-3 loads (in flight under k9 0-2 compute) ---
    float pre[4][8];
#pragma unroll
    for (int it = 0; it < 4; ++it) {
        int u = 16 + it*4 + wv;
        int g = u & 7, r = u >> 3;          // r in {2,3}
        int gr = h0 - 1 + r;                // h0+1 (valid), h0+2 (may be H_)
        if ((unsigned)gr < (unsigned)H_) {  // wave-uniform
            const float* src = xf + (size_t)(g*8)*HWsz + (size_t)gr*W_ + w0 + lane;
#pragma unroll
            for (int j = 0; j < 8; ++j) pre[it][j] = src[(size_t)j*HWsz];
        } else {
#pragma unroll
            for (int j = 0; j < 8; ++j) pre[it][j] = 0.f;
        }
    }
    float preh[8];
    if (tid < 32) {
        int c2 = tid & 1, g = (tid >> 1) & 7, r2 = ((tid >> 4) & 1) + 2;
        int gr = h0 - 1 + r2, gc = w0 - 1 + c2*65;
        bool ok = ((unsigned)gr < (unsigned)H_) && ((unsigned)gc < (unsigned)W_);
        int grc = min(gr, H_-1);
        const float* src = xf + (size_t)(g*8)*HWsz + (size_t)grc*W_ + max(gc, 0);
#pragma unroll
        for (int j = 0; j < 8; ++j) preh[j] = ok ? src[(size_t)j*HWsz] : 0.f;
    }

    // --- chunk0: k9 = 0..2 (fe rows 0-1 only), halves sequential (low VGPR) ---
    const int nt = wv & 1, rh = wv >> 1;
    const int l31 = lane & 31, l5 = lane >> 5;
    const int hC = h0 + rh;

    const f32x16 fz16 = {0.f,0.f,0.f,0.f,0.f,0.f,0.f,0.f,0.f,0.f,0.f,0.f,0.f,0.f,0.f,0.f};
    f32x16 fin[2] = {fz16, fz16};

#pragma unroll
    for (int k9 = 0; k9 < 3; ++k9) {
        const int rr = rh;                   // k9/3 == 0
        const int dwp = k9;
        s16x8 aw[4];
#pragma unroll
        for (int ks = 0; ks < 4; ++ks)
            aw[ks] = *(const s16x8*)(BwS + (size_t)((((k9<<2) + ks)*2 + nt) << 9) + lane*8);
#pragma unroll
        for (int half = 0; half < 2; ++half) {
            int col = half*32 + l31 + dwp;
            f32x16 tmp = fz16;
#pragma unroll
            for (int ks = 0; ks < 4; ++ks) {
                s16x8 bfr = *(const s16x8*)&fe[rr][ks*2 + l5][col][0];
                tmp = __builtin_amdgcn_mfma_f32_32x32x16_bf16(aw[ks], bfr, tmp, 0, 0, 0);
            }
            float wsc = swl[rh][k9][half*32 + l31];
#pragma unroll
            for (int c = 0; c < 16; ++c) fin[half][c] += wsc * tmp[c];
        }
    }

    // --- write rows 2-3 (loads have had k9 0-2 to land) ---
#pragma unroll
    for (int it = 0; it < 4; ++it) {
        int u = 16 + it*4 + wv;
        int g = u & 7, r = u >> 3;
        uint4 q;
        q.x = pack2bf(pre[it][0], pre[it][1]); q.y = pack2bf(pre[it][2], pre[it][3]);
        q.z = pack2bf(pre[it][4], pre[it][5]); q.w = pack2bf(pre[it][6], pre[it][7]);
        *(uint4*)&fe[r][g][1 + lane][0] = q;
    }
    if (tid < 32) {
        int c2 = tid & 1, g = (tid >> 1) & 7, r2 = ((tid >> 4) & 1) + 2;
        uint4 q;
        q.x = pack2bf(preh[0], preh[1]); q.y = pack2bf(preh[2], preh[3]);
        q.z = pack2bf(preh[4], preh[5]); q.w = pack2bf(preh[6], preh[7]);
        *(uint4*)&fe[r2][g][c2*65][0] = q;
    }
    __syncthreads();

    // --- chunk1: k9 = 3..8 with distance-1 aw prefetch, halves interleaved ---
    s16x8 awb[2][4];
#pragma unroll
    for (int ks = 0; ks < 4; ++ks)
        awb[1][ks] = *(const s16x8*)(BwS + (size_t)(((12 + ks)*2 + nt) << 9) + lane*8);
#pragma unroll
    for (int k9 = 3; k9 < 9; ++k9) {
        const int cur = k9 & 1, nxt = cur ^ 1;
        if (k9 < 8) {
#pragma unroll
            for (int ks = 0; ks < 4; ++ks)
                awb[nxt][ks] = *(const s16x8*)(BwS + (size_t)(((((k9+1)<<2) + ks)*2 + nt) << 9) + lane*8);
        }
        const int rr = rh + k9/3;
        const int dwp = k9 % 3;
        f32x16 tmp0 = fz16, tmp1 = fz16;
        const int col0 = l31 + dwp, col1 = 32 + l31 + dwp;
#pragma unroll
        for (int ks = 0; ks < 4; ++ks) {
            s16x8 b0 = *(const s16x8*)&fe[rr][ks*2 + l5][col0][0];
            s16x8 b1 = *(const s16x8*)&fe[rr][ks*2 + l5][col1][0];
            tmp0 = __builtin_amdgcn_mfma_f32_32x32x16_bf16(awb[cur][ks], b0, tmp0, 0, 0, 0);
            tmp1 = __builtin_amdgcn_mfma_f32_32x32x16_bf16(awb[cur][ks], b1, tmp1, 0, 0, 0);
        }
        float w0s = swl[rh][k9][l31];
        float w1s = swl[rh][k9][32 + l31];
#pragma unroll
        for (int c = 0; c < 16; ++c) {
            fin[0][c] += w0s * tmp0[c];
            fin[1][c] += w1s * tmp1[c];
        }
    }

    // --- epilogue: BN2 + ReLU, coalesced dword stores (128B segments) ---
    int obase = nt*32 + 4*l5;
#pragma unroll
    for (int half = 0; half < 2; ++half) {
        float* od = out + (((size_t)b*COUT + obase)*H_ + hC)*W_ + w0 + half*32 + l31;
#pragma unroll
        for (int v = 0; v < 4; ++v) {
            f32x4 sc4 = *(const f32x4*)&sbn[0][obase + 8*v];
            f32x4 tc4 = *(const f32x4*)&sbn[1][obase + 8*v];
#pragma unroll
            for (int c = 0; c < 4; ++c)
                od[(size_t)(8*v + c)*HWsz] =
                    fmaxf(fmaf(fin[half][4*v + c], sc4[c], tc4[c]), 0.f);
        }
    }
}

extern "C" void kernel_launch(void* const* d_in, const int* in_sizes, int n_in,
                              void* d_out, int out_size, void* d_ws, size_t ws_size,
                              hipStream_t stream)
{
    const float* x    = (const float*)d_in[0];
    const int*   mask = (const int*)d_in[1];
    const float* W1   = (const float*)d_in[2];
    const float* g1   = (const float*)d_in[3];
    const float* b1   = (const float*)d_in[4];
    const float* m1   = (const float*)d_in[5];
    const float* v1   = (const float*)d_in[6];
    const float* W2   = (const float*)d_in[7];
    const float* b2   = (const float*)d_in[8];
    const float* Wagg = (const float*)d_in[9];
    const float* g2   = (const float*)d_in[10];
    const float* bb2  = (const float*)d_in[11];
    const float* m2   = (const float*)d_in[12];
    const float* v2   = (const float*)d_in[13];
    float* outp = (float*)d_out;

    char* ws = (char*)d_ws;
    unsigned short* BwS   = (unsigned short*)(ws + 0);       // 73,728 B
    float*          Wfold = (float*)(ws + 73728);            //  2,052 B
    float*          sws   = (float*)(ws + 76800);            // 9,437,184 B

    hipLaunchKernelGGL(prep_bw, dim3(18), dim3(256), 0, stream,
                       Wagg, W1, g1, b1, m1, v1, W2, BwS, Wfold);
    hipLaunchKernelGGL(sw_k, dim3(W_/64, 64), dim3(512), 0, stream,
                       x, mask, Wfold, b2, sws);
    hipLaunchKernelGGL(agg_k, dim3(W_/64, 64), dim3(256), 0, stream,
                       x, sws, BwS, g2, bb2, m2, v2, outp);
}

// Round 5
// 314.294 us; speedup vs baseline: 1.0728x; 1.0728x over previous
//
#include <hip/hip_runtime.h>
#include <hip/hip_bf16.h>

#define H_ 64
#define W_ 2048
#define HWsz (H_*W_)
#define CIN 64
#define CTOT 68
#define COUT 64

typedef float  f32x2  __attribute__((ext_vector_type(2)));
typedef float  f32x4  __attribute__((ext_vector_type(4)));
typedef float  f32x16 __attribute__((ext_vector_type(16)));
typedef short  s16x8  __attribute__((ext_vector_type(8)));

__device__ __forceinline__ unsigned short f2bf(float f) {
    unsigned u = __builtin_bit_cast(unsigned, f);
    unsigned r = u + 0x7fffu + ((u >> 16) & 1u);   // RNE; inputs finite
    return (unsigned short)(r >> 16);
}

__device__ __forceinline__ unsigned pack2bf(float a, float b) {
    __hip_bfloat162 h = __float22bfloat162_rn(float2{a, b});   // v_cvt_pk_bf16_f32
    unsigned u;
    __builtin_memcpy(&u, &h, 4);
    return u;
}

// async 16B/lane global->LDS copy: wave-uniform LDS base, per-lane global src.
// dest(lane) = lbase + lane*16  (fe inner dim is exactly 16B -> linear, no pad)
__device__ __forceinline__ void gl_lds16(const unsigned short* g, unsigned short* l) {
    __builtin_amdgcn_global_load_lds(
        (const __attribute__((address_space(1))) unsigned int*)g,
        (__attribute__((address_space(3))) unsigned int*)l,
        16, 0, 0);
}

// ---------------- prep: Wagg -> bf16 MFMA A-fragments; fold BN1 ----------------
// BwS idx lane l: o = nt*32+(l&31), ch = ks*16+(l>>5)*8+j  (A[m=o][k=ch] layout)
__global__ __launch_bounds__(256) void prep_bw(
    const float* __restrict__ Wagg,
    const float* __restrict__ W1, const float* __restrict__ g1,
    const float* __restrict__ b1, const float* __restrict__ m1,
    const float* __restrict__ v1, const float* __restrict__ W2,
    unsigned short* __restrict__ BwS, float* __restrict__ Wfold)
{
    int tid = threadIdx.x;
    if (blockIdx.x == 0) {
        if (tid < 64) {
            float s1 = g1[tid] * rsqrtf(v1[tid] + 1e-5f);
#pragma unroll
            for (int m = 0; m < 4; ++m) Wfold[tid*8 + m] = W1[tid*4 + m] * s1;
            Wfold[tid*8 + 4] = b1[tid] - m1[tid]*s1;
            Wfold[tid*8 + 5] = W2[tid];
            Wfold[tid*8 + 6] = 0.f;
            Wfold[tid*8 + 7] = 0.f;
        }
        __syncthreads();
        if (tid == 0) {
            float s = 0.f;
            for (int c = 0; c < 64; ++c) s += fmaxf(Wfold[c*8 + 4], 0.f) * Wfold[c*8 + 5];
            Wfold[512] = s;
        }
    }
    int idx = blockIdx.x * 256 + tid;
    if (idx < 4608) {
        int lane = idx & 63;
        int rest = idx >> 6;
        int nt = rest & 1;
        int ks = (rest >> 1) & 3;
        int k9 = rest >> 3;
        int o  = nt*32 + (lane & 31);
        int ch = ks*16 + (lane >> 5)*8;
        const float* src = Wagg + (size_t)o*(9*CIN) + k9*64 + ch;
        s16x8 v8;
#pragma unroll
        for (int j = 0; j < 8; ++j) v8[j] = (short)f2bf(src[j]);
        *(s16x8*)(BwS + (size_t)idx*8) = v8;
    }
}

// ---------------- sw_k: logits + softmax -> sws; feats -> xg (bf16, frag layout) ----
// Block 512 thr, tile = 2 rows x 64 px. wave = (rowq = wv>>2, tg = wv&3),
// 2 taps/thread packed f32x2. Also converts this tile's 2 feat rows to
// xg[b][h][g][w][8ch] bf16 (16 strided loads/thread, overlapping logit VALU).
__global__ __launch_bounds__(512, 6) void sw_k(
    const float* __restrict__ x, const int* __restrict__ mask,
    const float* __restrict__ Wfold, const float* __restrict__ b2p,
    float* __restrict__ sws, unsigned short* __restrict__ xg)
{
    __shared__ float sw[2][9][64];

    const int tid = threadIdx.x;
    const int bx = blockIdx.x, by = blockIdx.y;
    const int b = by >> 5, h0 = (by & 31) << 1;
    const int w0 = bx << 6;
    const int lane = tid & 63, wv = tid >> 6;

    const float* xp = x + (size_t)b*CTOT*HWsz;         // pos channels 0..3
    const float* xf = x + ((size_t)b*CTOT + 4)*HWsz;   // feat channels
    const int*   mk = mask + (size_t)b*HWsz;

    // --- transform loads (issued early; land under logit VALU) ---
    // chunk id = tid + 512*cc: rq = id>>9, g = (id>>6)&7, px = id&63
    float tv[2][8];
#pragma unroll
    for (int cc = 0; cc < 2; ++cc) {
        int id = tid + (cc << 9);
        int rq = id >> 9, g = (id >> 6) & 7, pxx = id & 63;
        const float* src = xf + (size_t)(g*8)*HWsz + (size_t)(h0 + rq)*W_ + w0 + pxx;
#pragma unroll
        for (int j = 0; j < 8; ++j) tv[cc][j] = src[(size_t)j*HWsz];
    }

    const int px = lane, gw = w0 + px;
    const int rowq = wv >> 2, tg = wv & 3;
    const int h = h0 + rowq;
    const int ka = 2*tg + (tg >> 1);        // tg 0..3 -> taps {0,1},{2,3},{5,6},{7,8}

    float pc[4];
#pragma unroll
    for (int ch = 0; ch < 4; ++ch) pc[ch] = xp[(size_t)ch*HWsz + (size_t)h*W_ + gw];

    f32x2 dd[4]; f32x2 mu;
#pragma unroll
    for (int i = 0; i < 2; ++i) {
        int k = ka + i;
        int r = k/3 - 1, d = k%3 - 1;
        int ih = h + r, iw = gw + d;
        bool ok = ((unsigned)ih < (unsigned)H_) && ((unsigned)iw < (unsigned)W_);
        int ihc = min(max(ih, 0), H_-1);
        int iwc = min(max(iw, 0), W_-1);
        mu[i] = ok ? (float)mk[(size_t)ihc*W_ + iwc] : 0.f;
#pragma unroll
        for (int ch = 0; ch < 4; ++ch) {
            float p = xp[(size_t)ch*HWsz + (size_t)ihc*W_ + iwc];
            dd[ch][i] = (ok ? p : 0.f) - pc[ch];   // reference zero-pads pn
        }
    }

    const f32x4* Wf4 = (const f32x4*)Wfold;
    const f32x2 z2 = {0.f, 0.f};
    f32x2 lg = z2;
#pragma unroll 8
    for (int c = 0; c < CIN; ++c) {
        f32x4 wa = Wf4[2*c];        // wave-uniform s_load
        f32x4 wb = Wf4[2*c + 1];
        f32x2 v = {wb[0], wb[0]};
        v = dd[0]*wa[0] + v;          // packed f32x2 fma
        v = dd[1]*wa[1] + v;
        v = dd[2]*wa[2] + v;
        v = dd[3]*wa[3] + v;
        v = __builtin_elementwise_max(v, z2);
        lg = v*wb[1] + lg;
    }
    float b2v = b2p[0];
    sw[rowq][ka    ][px] = (lg[0] + b2v) * mu[0];
    sw[rowq][ka + 1][px] = (lg[1] + b2v) * mu[1];

    // --- pack + store xg (coalesced 16B/lane, 1KB segments) ---
#pragma unroll
    for (int cc = 0; cc < 2; ++cc) {
        int id = tid + (cc << 9);
        int rq = id >> 9, g = (id >> 6) & 7, pxx = id & 63;
        uint4 q;
        q.x = pack2bf(tv[cc][0], tv[cc][1]); q.y = pack2bf(tv[cc][2], tv[cc][3]);
        q.z = pack2bf(tv[cc][4], tv[cc][5]); q.w = pack2bf(tv[cc][6], tv[cc][7]);
        *(uint4*)(xg + ((((size_t)(b*H_ + h0 + rq)*8 + g)*W_) + w0 + pxx)*8) = q;
    }
    __syncthreads();

    // softmax over 9 taps (128 threads) -> global sws
    if (tid < 128) {
        int rq = tid >> 6, p2 = tid & 63;
        float mu4 = (float)mk[(size_t)(h0 + rq)*W_ + w0 + p2];
        float lgv[9];
#pragma unroll
        for (int k = 0; k < 9; ++k) if (k != 4) lgv[k] = sw[rq][k][p2];
        lgv[4] = (Wfold[512] + b2v) * mu4;
        float mx = -1e30f;
#pragma unroll
        for (int k = 0; k < 9; ++k) mx = fmaxf(mx, lgv[k]);
        float s = 0.f, e[9];
#pragma unroll
        for (int k = 0; k < 9; ++k) { e[k] = __expf(lgv[k] - mx); s += e[k]; }
        float inv = 1.f / s;
        float* dst = sws + ((size_t)(b*H_ + h0 + rq)*9)*W_ + w0 + p2;
#pragma unroll
        for (int k = 0; k < 9; ++k) dst[(size_t)k*W_] = e[k] * inv;
    }
}

// ---------------- agg_k: async-stage xg -> weighted MFMA -> BN2 epilogue ----------------
// Block 256 thr (4 waves). Interior staging = 32 global_load_lds calls
// (1KB each, zero VGPR/VALU). MFMA phase: aw distance-1 ping-pong from L2.
__global__ __launch_bounds__(256, 4) void agg_k(
    const unsigned short* __restrict__ xg, const float* __restrict__ sws,
    const unsigned short* __restrict__ BwS,
    const float* __restrict__ g2, const float* __restrict__ bb2,
    const float* __restrict__ m2, const float* __restrict__ v2,
    float* __restrict__ out)
{
    __shared__ __align__(16) unsigned short fe[4][8][66][8];   // 33,792 B
    __shared__ __align__(16) float swl[2][9][64];              //  4,608 B
    __shared__ __align__(16) float sbn[2][64];                 //    512 B

    const int tid = threadIdx.x;
    const int bx = blockIdx.x, by = blockIdx.y;
    const int b = by >> 5, h0 = (by & 31) << 1;
    const int w0 = bx << 6;
    const int lane = tid & 63, wv = tid >> 6;

    // --- interior staging: async, 8 (r,g) tasks per wave ---
#pragma unroll
    for (int it = 0; it < 8; ++it) {
        int u = it*4 + wv;                  // wave-uniform
        int g = u & 7, r = u >> 3;
        int gr = h0 - 1 + r;
        if ((unsigned)gr < (unsigned)H_) {
            const unsigned short* src =
                xg + ((((size_t)(b*H_ + gr)*8 + g)*W_) + w0 + lane)*8;
            gl_lds16(src, &fe[r][g][1][0]);
        } else {
            uint4 z = {0u, 0u, 0u, 0u};
            *(uint4*)&fe[r][g][1 + lane][0] = z;
        }
    }
    // --- halo: 64 tasks (2 cols x 8 g x 4 r), 16B each ---
    if (tid < 64) {
        int c2 = tid & 1, g = (tid >> 1) & 7, r = tid >> 4;
        int gr = h0 - 1 + r, gc = w0 - 1 + c2*65;
        uint4 q = {0u, 0u, 0u, 0u};
        if (((unsigned)gr < (unsigned)H_) && ((unsigned)gc < (unsigned)W_))
            q = *(const uint4*)(xg + ((((size_t)(b*H_ + gr)*8 + g)*W_) + gc)*8);
        *(uint4*)&fe[r][g][c2*65][0] = q;
    }
    // BN2 table: tid in [64,128)
    if (tid >= 64 && tid < 128) {
        int o = tid - 64;
        float sc = g2[o] * rsqrtf(v2[o] + 1e-5f);
        sbn[0][o] = sc;
        sbn[1][o] = bb2[o] - m2[o]*sc;
    }
    // softmax weights -> LDS: tid in [128,256)
    if (tid >= 128) {
        int idx = tid - 128;
        int rq = idx >> 6, p2 = idx & 63;
        const float* sp = sws + ((size_t)(b*H_ + h0 + rq)*9)*W_ + w0 + p2;
#pragma unroll
        for (int k = 0; k < 9; ++k) swl[rq][k][p2] = sp[(size_t)k*W_];
    }

    // prefetch k9=0 A-fragments before the barrier (overlaps staging drain)
    const int nt = wv & 1, rh = wv >> 1;
    const int l31 = lane & 31, l5 = lane >> 5;
    const int hC = h0 + rh;
    s16x8 aw[4];
#pragma unroll
    for (int ks = 0; ks < 4; ++ks)
        aw[ks] = *(const s16x8*)(BwS + (size_t)((ks*2 + nt) << 9) + lane*8);

    __syncthreads();

    // --- MFMA: A=Wagg fragments (L2), B=feats (LDS); distance-1 aw prefetch ---
    const f32x16 fz16 = {0.f,0.f,0.f,0.f,0.f,0.f,0.f,0.f,0.f,0.f,0.f,0.f,0.f,0.f,0.f,0.f};
    f32x16 fin[2] = {fz16, fz16};

#pragma unroll
    for (int k9 = 0; k9 < 9; ++k9) {
        s16x8 awn[4];
        if (k9 < 8) {
#pragma unroll
            for (int ks = 0; ks < 4; ++ks)
                awn[ks] = *(const s16x8*)(BwS + (size_t)((((k9+1)*4 + ks)*2 + nt) << 9) + lane*8);
        }
        const int rr = rh + k9/3;            // fe row (fe[0] = global row h0-1)
        const int dwp = k9 % 3;
#pragma unroll
        for (int half = 0; half < 2; ++half) {
            int col = half*32 + l31 + dwp;   // 1 + px + (dwp-1)
            f32x16 tmp = fz16;
#pragma unroll
            for (int ks = 0; ks < 4; ++ks) {
                s16x8 bfr = *(const s16x8*)&fe[rr][ks*2 + l5][col][0];
                tmp = __builtin_amdgcn_mfma_f32_32x32x16_bf16(aw[ks], bfr, tmp, 0, 0, 0);
            }
            float wsc = swl[rh][k9][half*32 + l31];
#pragma unroll
            for (int c = 0; c < 16; ++c) fin[half][c] += wsc * tmp[c];
        }
        if (k9 < 8) {
#pragma unroll
            for (int ks = 0; ks < 4; ++ks) aw[ks] = awn[ks];
        }
    }

    // --- epilogue: BN2 + ReLU, coalesced dword stores (128B segments) ---
    int obase = nt*32 + 4*l5;
#pragma unroll
    for (int half = 0; half < 2; ++half) {
        float* od = out + (((size_t)b*COUT + obase)*H_ + hC)*W_ + w0 + half*32 + l31;
#pragma unroll
        for (int v = 0; v < 4; ++v) {
            f32x4 sc4 = *(const f32x4*)&sbn[0][obase + 8*v];
            f32x4 tc4 = *(const f32x4*)&sbn[1][obase + 8*v];
#pragma unroll
            for (int c = 0; c < 4; ++c)
                od[(size_t)(8*v + c)*HWsz] =
                    fmaxf(fmaf(fin[half][4*v + c], sc4[c], tc4[c]), 0.f);
        }
    }
}

extern "C" void kernel_launch(void* const* d_in, const int* in_sizes, int n_in,
                              void* d_out, int out_size, void* d_ws, size_t ws_size,
                              hipStream_t stream)
{
    const float* x    = (const float*)d_in[0];
    const int*   mask = (const int*)d_in[1];
    const float* W1   = (const float*)d_in[2];
    const float* g1   = (const float*)d_in[3];
    const float* b1   = (const float*)d_in[4];
    const float* m1   = (const float*)d_in[5];
    const float* v1   = (const float*)d_in[6];
    const float* W2   = (const float*)d_in[7];
    const float* b2   = (const float*)d_in[8];
    const float* Wagg = (const float*)d_in[9];
    const float* g2   = (const float*)d_in[10];
    const float* bb2  = (const float*)d_in[11];
    const float* m2   = (const float*)d_in[12];
    const float* v2   = (const float*)d_in[13];
    float* outp = (float*)d_out;

    char* ws = (char*)d_ws;
    unsigned short* BwS   = (unsigned short*)(ws + 0);       // 73,728 B
    float*          Wfold = (float*)(ws + 73728);            //  2,052 B
    float*          sws   = (float*)(ws + 76800);            // 9,437,184 B
    unsigned short* xg    = (unsigned short*)(ws + 9513984); // 33,554,432 B

    hipLaunchKernelGGL(prep_bw, dim3(18), dim3(256), 0, stream,
                       Wagg, W1, g1, b1, m1, v1, W2, BwS, Wfold);
    hipLaunchKernelGGL(sw_k, dim3(W_/64, 64), dim3(512), 0, stream,
                       x, mask, Wfold, b2, sws, xg);
    hipLaunchKernelGGL(agg_k, dim3(W_/64, 64), dim3(256), 0, stream,
                       xg, sws, BwS, g2, bb2, m2, v2, outp);
}

// Round 6
// 195.862 us; speedup vs baseline: 1.7215x; 1.6047x over previous
//
#include <hip/hip_runtime.h>
#include <hip/hip_bf16.h>

#define H_ 64
#define W_ 2048
#define HWsz (H_*W_)
#define CIN 64
#define CTOT 68
#define COUT 64

typedef float  f32x2  __attribute__((ext_vector_type(2)));
typedef float  f32x4  __attribute__((ext_vector_type(4)));
typedef float  f32x16 __attribute__((ext_vector_type(16)));
typedef short  s16x8  __attribute__((ext_vector_type(8)));

__device__ __forceinline__ unsigned short f2bf(float f) {
    unsigned u = __builtin_bit_cast(unsigned, f);
    unsigned r = u + 0x7fffu + ((u >> 16) & 1u);   // RNE; inputs finite
    return (unsigned short)(r >> 16);
}

__device__ __forceinline__ unsigned pack2bf(float a, float b) {
    __hip_bfloat162 h = __float22bfloat162_rn(float2{a, b});   // v_cvt_pk_bf16_f32
    unsigned u;
    __builtin_memcpy(&u, &h, 4);
    return u;
}

// ---------------- prep: Wagg -> bf16 MFMA A-fragments; fold BN1 ----------------
// BwS idx lane l: o = nt*32+(l&31), ch = ks*16+(l>>5)*8+j  (A[m=o][k=ch] layout)
__global__ __launch_bounds__(256) void prep_bw(
    const float* __restrict__ Wagg,
    const float* __restrict__ W1, const float* __restrict__ g1,
    const float* __restrict__ b1, const float* __restrict__ m1,
    const float* __restrict__ v1, const float* __restrict__ W2,
    unsigned short* __restrict__ BwS, float* __restrict__ Wfold)
{
    int tid = threadIdx.x;
    if (blockIdx.x == 0) {
        if (tid < 64) {
            float s1 = g1[tid] * rsqrtf(v1[tid] + 1e-5f);
#pragma unroll
            for (int m = 0; m < 4; ++m) Wfold[tid*8 + m] = W1[tid*4 + m] * s1;
            Wfold[tid*8 + 4] = b1[tid] - m1[tid]*s1;
            Wfold[tid*8 + 5] = W2[tid];
            Wfold[tid*8 + 6] = 0.f;
            Wfold[tid*8 + 7] = 0.f;
        }
        __syncthreads();
        if (tid == 0) {
            float s = 0.f;
            for (int c = 0; c < 64; ++c) s += fmaxf(Wfold[c*8 + 4], 0.f) * Wfold[c*8 + 5];
            Wfold[512] = s;
        }
    }
    int idx = blockIdx.x * 256 + tid;
    if (idx < 4608) {
        int lane = idx & 63;
        int rest = idx >> 6;
        int nt = rest & 1;
        int ks = (rest >> 1) & 3;
        int k9 = rest >> 3;
        int o  = nt*32 + (lane & 31);
        int ch = ks*16 + (lane >> 5)*8;
        const float* src = Wagg + (size_t)o*(9*CIN) + k9*64 + ch;
        s16x8 v8;
#pragma unroll
        for (int j = 0; j < 8; ++j) v8[j] = (short)f2bf(src[j]);
        *(s16x8*)(BwS + (size_t)idx*8) = v8;
    }
}

// ---------------- mega: stage + logits + softmax + MFMA + epilogue ----------------
// Block 512 thr (8 waves), tile = 2 rows x 64 px x 64 out.
// launch_bounds(512,4): VGPR cap 128 -> scheduler has lookahead room (R1's cap-64
// allocation had none); ~2 blocks/CU resident (occupancy proven non-binding R0/R1).
// pos+mask staged to LDS (clamps paid once); feats staged via f32x2 loads;
// phase C: one half per wave, fin=16 regs, aw distance-1 ping-pong (32 regs).
__global__ __launch_bounds__(512, 4) void mega_k(
    const float* __restrict__ x, const int* __restrict__ mask,
    const unsigned short* __restrict__ BwS, const float* __restrict__ Wfold,
    const float* __restrict__ b2p,
    const float* __restrict__ g2, const float* __restrict__ bb2,
    const float* __restrict__ m2, const float* __restrict__ v2,
    float* __restrict__ out)
{
    __shared__ __align__(16) unsigned short fe[4][8][66][8];   // 33,792 B
    __shared__ __align__(16) float sw[2][9][64];               //  4,608 B
    __shared__ __align__(16) float posl[4][66][4];             //  4,224 B
    __shared__ __align__(16) float mskl[4][66];                //  1,056 B
    __shared__ __align__(16) float sbn[2][64];                 //    512 B

    const int tid = threadIdx.x;
    const int bx = blockIdx.x, by = blockIdx.y;
    const int b = by >> 5, h0 = (by & 31) << 1;
    const int w0 = bx << 6;
    const int lane = tid & 63, wv = tid >> 6;

    const float* xf = x + ((size_t)b*CTOT + 4)*HWsz;   // feat channels
    const float* xp = x + (size_t)b*CTOT*HWsz;         // pos channels 0..3
    const int*   mk = mask + (size_t)b*HWsz;

    // --- staging: interior feats. 1024 tasks (r,g,px2), 2/thread, f32x2 loads ---
#pragma unroll
    for (int cc = 0; cc < 2; ++cc) {
        int task = tid + (cc << 9);
        int px2 = task & 31, g = (task >> 5) & 7, r = task >> 8;
        int gr = h0 - 1 + r;
        uint4 q0 = {0u,0u,0u,0u}, q1 = {0u,0u,0u,0u};
        if ((unsigned)gr < (unsigned)H_) {              // wave-uniform branch
            const float* src = xf + (size_t)(g*8)*HWsz + (size_t)gr*W_ + w0 + 2*px2;
            f32x2 v[8];
#pragma unroll
            for (int j = 0; j < 8; ++j) v[j] = *(const f32x2*)(src + (size_t)j*HWsz);
            q0.x = pack2bf(v[0][0], v[1][0]); q0.y = pack2bf(v[2][0], v[3][0]);
            q0.z = pack2bf(v[4][0], v[5][0]); q0.w = pack2bf(v[6][0], v[7][0]);
            q1.x = pack2bf(v[0][1], v[1][1]); q1.y = pack2bf(v[2][1], v[3][1]);
            q1.z = pack2bf(v[4][1], v[5][1]); q1.w = pack2bf(v[6][1], v[7][1]);
        }
        *(uint4*)&fe[r][g][1 + 2*px2][0] = q0;
        *(uint4*)&fe[r][g][2 + 2*px2][0] = q1;
    }
    // --- halo feats: 64 tasks (2 cols x 8 g x 4 r), scalar loads ---
    if (tid < 64) {
        int c2 = tid & 1, g = (tid >> 1) & 7, r = tid >> 4;
        int gr = h0 - 1 + r, gc = w0 - 1 + c2*65;
        uint4 q = {0u, 0u, 0u, 0u};
        if (((unsigned)gr < (unsigned)H_) && ((unsigned)gc < (unsigned)W_)) {
            const float* src = xf + (size_t)(g*8)*HWsz + (size_t)gr*W_ + gc;
            float v[8];
#pragma unroll
            for (int j = 0; j < 8; ++j) v[j] = src[(size_t)j*HWsz];
            q.x = pack2bf(v[0], v[1]); q.y = pack2bf(v[2], v[3]);
            q.z = pack2bf(v[4], v[5]); q.w = pack2bf(v[6], v[7]);
        }
        *(uint4*)&fe[r][g][c2*65][0] = q;
    }
    // --- pos + mask -> LDS: 264 tasks (r, col), zero-padded halo ---
    if (tid >= 64 && tid < 64 + 264) {
        int idx = tid - 64;
        int r = idx / 66, col = idx - r*66;
        int gr = h0 - 1 + r, gc = w0 - 1 + col;
        bool ok = ((unsigned)gr < (unsigned)H_) && ((unsigned)gc < (unsigned)W_);
        size_t off = (size_t)max(gr,0)*W_ + max(gc,0);
        f32x4 p4 = {0.f, 0.f, 0.f, 0.f};
        float mval = 0.f;
        if (ok) {
#pragma unroll
            for (int ch = 0; ch < 4; ++ch) p4[ch] = xp[(size_t)ch*HWsz + off];
            mval = (float)mk[off];
        }
        *(f32x4*)&posl[r][col][0] = p4;
        mskl[r][col] = mval;
    }
    // --- BN2 table: last wave ---
    if (tid >= 448) {
        int o = tid - 448;
        float sc = g2[o] * rsqrtf(v2[o] + 1e-5f);
        sbn[0][o] = sc;
        sbn[1][o] = bb2[o] - m2[o]*sc;
    }
    __syncthreads();

    // --- Phase A: logits. wave = (rowq = wv>>2, tg = wv&3), 2 taps/thread ---
    const int px = lane;
    const int rowq = wv >> 2, tg = wv & 3;
    const int ka = 2*tg + (tg >> 1);        // tg 0..3 -> taps {0,1},{2,3},{5,6},{7,8}

    f32x4 pcv = *(const f32x4*)&posl[rowq + 1][1 + px][0];

    f32x2 dd[4]; f32x2 mu;
#pragma unroll
    for (int i = 0; i < 2; ++i) {
        int k = ka + i;
        int dr = k/3 - 1, dc = k%3 - 1;
        f32x4 pv = *(const f32x4*)&posl[rowq + 1 + dr][1 + px + dc][0];
        mu[i] = mskl[rowq + 1 + dr][1 + px + dc];
#pragma unroll
        for (int ch = 0; ch < 4; ++ch) dd[ch][i] = pv[ch] - pcv[ch];
    }

    const f32x4* Wf4 = (const f32x4*)Wfold;
    const f32x2 z2 = {0.f, 0.f};
    f32x2 lg = z2;
#pragma unroll 8
    for (int c = 0; c < CIN; ++c) {
        f32x4 wa = Wf4[2*c];        // wave-uniform s_load
        f32x4 wb = Wf4[2*c + 1];
        f32x2 v = {wb[0], wb[0]};
        v = dd[0]*wa[0] + v;          // packed f32x2 fma
        v = dd[1]*wa[1] + v;
        v = dd[2]*wa[2] + v;
        v = dd[3]*wa[3] + v;
        v = __builtin_elementwise_max(v, z2);
        lg = v*wb[1] + lg;
    }
    float b2v = b2p[0];
    sw[rowq][ka    ][px] = (lg[0] + b2v) * mu[0];
    sw[rowq][ka + 1][px] = (lg[1] + b2v) * mu[1];
    __syncthreads();

    // --- Phase B: softmax (128 threads: row x px) ---
    if (tid < 128) {
        int rq = tid >> 6, p2 = tid & 63;
        float mu4 = mskl[rq + 1][1 + p2];
        float lgv[9];
#pragma unroll
        for (int k = 0; k < 9; ++k) if (k != 4) lgv[k] = sw[rq][k][p2];
        lgv[4] = (Wfold[512] + b2v) * mu4;
        float mx = -1e30f;
#pragma unroll
        for (int k = 0; k < 9; ++k) mx = fmaxf(mx, lgv[k]);
        float s = 0.f, e[9];
#pragma unroll
        for (int k = 0; k < 9; ++k) { e[k] = __expf(lgv[k] - mx); s += e[k]; }
        float inv = 1.f / s;
#pragma unroll
        for (int k = 0; k < 9; ++k) sw[rq][k][p2] = e[k] * inv;
    }
    __syncthreads();

    // --- Phase C: MFMA. wave = (nt = wv&1, rh = (wv>>1)&1, hv = wv>>2) ---
    const int nt = wv & 1, rh = (wv >> 1) & 1, hv = wv >> 2;
    const int l31 = lane & 31, l5 = lane >> 5;
    const int hC = h0 + rh;

    const f32x16 fz16 = {0.f,0.f,0.f,0.f,0.f,0.f,0.f,0.f,0.f,0.f,0.f,0.f,0.f,0.f,0.f,0.f};
    f32x16 fin = fz16;

    // aw distance-1 ping-pong (fits: fin 16 + tmp 16 + awp 32 < cap 128)
    s16x8 awp[2][4];
#pragma unroll
    for (int ks = 0; ks < 4; ++ks)
        awp[0][ks] = *(const s16x8*)(BwS + (size_t)((ks*2 + nt) << 9) + lane*8);

#pragma unroll
    for (int k9 = 0; k9 < 9; ++k9) {
        const int cb = k9 & 1;
        if (k9 < 8) {
#pragma unroll
            for (int ks = 0; ks < 4; ++ks)
                awp[cb ^ 1][ks] = *(const s16x8*)(BwS +
                    (size_t)((((k9+1)*4 + ks)*2 + nt) << 9) + lane*8);
        }
        const int rr = rh + k9/3;            // fe row (fe[0] = global row h0-1)
        const int dwp = k9 % 3;
        const int col = hv*32 + l31 + dwp;   // 1 + px + (dwp-1)
        f32x16 tmp = fz16;
#pragma unroll
        for (int ks = 0; ks < 4; ++ks) {
            s16x8 bfr = *(const s16x8*)&fe[rr][ks*2 + l5][col][0];
            tmp = __builtin_amdgcn_mfma_f32_32x32x16_bf16(awp[cb][ks], bfr, tmp, 0, 0, 0);
        }
        float wsc = sw[rh][k9][hv*32 + l31];
        fin += tmp * wsc;                    // packed f32 fma (vectorized)
    }

    // --- epilogue: BN2 + ReLU, coalesced dword stores (128B segments) ---
    int obase = nt*32 + 4*l5;
    float* od = out + (((size_t)b*COUT + obase)*H_ + hC)*W_ + w0 + hv*32 + l31;
#pragma unroll
    for (int v = 0; v < 4; ++v) {
        f32x4 sc4 = *(const f32x4*)&sbn[0][obase + 8*v];
        f32x4 tc4 = *(const f32x4*)&sbn[1][obase + 8*v];
#pragma unroll
        for (int c = 0; c < 4; ++c)
            od[(size_t)(8*v + c)*HWsz] =
                fmaxf(fmaf(fin[4*v + c], sc4[c], tc4[c]), 0.f);
    }
}

extern "C" void kernel_launch(void* const* d_in, const int* in_sizes, int n_in,
                              void* d_out, int out_size, void* d_ws, size_t ws_size,
                              hipStream_t stream)
{
    const float* x    = (const float*)d_in[0];
    const int*   mask = (const int*)d_in[1];
    const float* W1   = (const float*)d_in[2];
    const float* g1   = (const float*)d_in[3];
    const float* b1   = (const float*)d_in[4];
    const float* m1   = (const float*)d_in[5];
    const float* v1   = (const float*)d_in[6];
    const float* W2   = (const float*)d_in[7];
    const float* b2   = (const float*)d_in[8];
    const float* Wagg = (const float*)d_in[9];
    const float* g2   = (const float*)d_in[10];
    const float* bb2  = (const float*)d_in[11];
    const float* m2   = (const float*)d_in[12];
    const float* v2   = (const float*)d_in[13];
    float* outp = (float*)d_out;

    char* ws = (char*)d_ws;
    unsigned short* BwS   = (unsigned short*)(ws + 0);      // 73,728 B
    float*          Wfold = (float*)(ws + 73728);           //  2,052 B

    hipLaunchKernelGGL(prep_bw, dim3(18), dim3(256), 0, stream,
                       Wagg, W1, g1, b1, m1, v1, W2, BwS, Wfold);
    hipLaunchKernelGGL(mega_k, dim3(W_/64, 64), dim3(512), 0, stream,
                       x, mask, BwS, Wfold, b2, g2, bb2, m2, v2, outp);
}

// Round 7
// 188.925 us; speedup vs baseline: 1.7848x; 1.0367x over previous
//
#include <hip/hip_runtime.h>
#include <hip/hip_bf16.h>

#define H_ 64
#define W_ 2048
#define HWsz (H_*W_)
#define CIN 64
#define CTOT 68
#define COUT 64

typedef float  f32x2  __attribute__((ext_vector_type(2)));
typedef float  f32x4  __attribute__((ext_vector_type(4)));
typedef float  f32x16 __attribute__((ext_vector_type(16)));
typedef short  s16x8  __attribute__((ext_vector_type(8)));

__device__ __forceinline__ unsigned short f2bf(float f) {
    unsigned u = __builtin_bit_cast(unsigned, f);
    unsigned r = u + 0x7fffu + ((u >> 16) & 1u);   // RNE; inputs finite
    return (unsigned short)(r >> 16);
}

__device__ __forceinline__ unsigned pack2bf(float a, float b) {
    __hip_bfloat162 h = __float22bfloat162_rn(float2{a, b});   // v_cvt_pk_bf16_f32
    unsigned u;
    __builtin_memcpy(&u, &h, 4);
    return u;
}

// async 16B/lane global->LDS copy: wave-uniform LDS base, per-lane global src.
// dest(lane) = lbase + lane*16  (fe inner dim is exactly 16B -> linear)
__device__ __forceinline__ void gl_lds16(const unsigned short* g, unsigned short* l) {
    __builtin_amdgcn_global_load_lds(
        (const __attribute__((address_space(1))) unsigned int*)g,
        (__attribute__((address_space(3))) unsigned int*)l,
        16, 0, 0);
}

// ---------------- prep: Wagg -> bf16 MFMA A-fragments; fold BN1 ----------------
// BwS idx lane l: o = nt*32+(l&31), ch = ks*16+(l>>5)*8+j  (A[m=o][k=ch] layout)
__global__ __launch_bounds__(256) void prep_bw(
    const float* __restrict__ Wagg,
    const float* __restrict__ W1, const float* __restrict__ g1,
    const float* __restrict__ b1, const float* __restrict__ m1,
    const float* __restrict__ v1, const float* __restrict__ W2,
    unsigned short* __restrict__ BwS, float* __restrict__ Wfold)
{
    int tid = threadIdx.x;
    if (blockIdx.x == 0) {
        if (tid < 64) {
            float s1 = g1[tid] * rsqrtf(v1[tid] + 1e-5f);
#pragma unroll
            for (int m = 0; m < 4; ++m) Wfold[tid*8 + m] = W1[tid*4 + m] * s1;
            Wfold[tid*8 + 4] = b1[tid] - m1[tid]*s1;
            Wfold[tid*8 + 5] = W2[tid];
            Wfold[tid*8 + 6] = 0.f;
            Wfold[tid*8 + 7] = 0.f;
        }
        __syncthreads();
        if (tid == 0) {
            float s = 0.f;
            for (int c = 0; c < 64; ++c) s += fmaxf(Wfold[c*8 + 4], 0.f) * Wfold[c*8 + 5];
            Wfold[512] = s;
        }
    }
    int idx = blockIdx.x * 256 + tid;
    if (idx < 4608) {
        int lane = idx & 63;
        int rest = idx >> 6;
        int nt = rest & 1;
        int ks = (rest >> 1) & 3;
        int k9 = rest >> 3;
        int o  = nt*32 + (lane & 31);
        int ch = ks*16 + (lane >> 5)*8;
        const float* src = Wagg + (size_t)o*(9*CIN) + k9*64 + ch;
        s16x8 v8;
#pragma unroll
        for (int j = 0; j < 8; ++j) v8[j] = (short)f2bf(src[j]);
        *(s16x8*)(BwS + (size_t)idx*8) = v8;
    }
}

// ---------------- sw_k: logits + softmax -> sws; feats -> xg (bf16, frag layout) ----
// Block 512 thr, tile = 2 rows x 64 px. wave = (rowq = wv>>2, tg = wv&3),
// 2 taps/thread packed f32x2. Also converts this tile's 2 feat rows to
// xg[b][h][g][w][8ch] bf16 (16 strided loads/thread, overlapping logit VALU).
__global__ __launch_bounds__(512, 6) void sw_k(
    const float* __restrict__ x, const int* __restrict__ mask,
    const float* __restrict__ Wfold, const float* __restrict__ b2p,
    float* __restrict__ sws, unsigned short* __restrict__ xg)
{
    __shared__ float sw[2][9][64];

    const int tid = threadIdx.x;
    const int bx = blockIdx.x, by = blockIdx.y;
    const int b = by >> 5, h0 = (by & 31) << 1;
    const int w0 = bx << 6;
    const int lane = tid & 63, wv = tid >> 6;

    const float* xp = x + (size_t)b*CTOT*HWsz;         // pos channels 0..3
    const float* xf = x + ((size_t)b*CTOT + 4)*HWsz;   // feat channels
    const int*   mk = mask + (size_t)b*HWsz;

    // --- transform loads (issued early; land under logit VALU) ---
    // chunk id = tid + 512*cc: rq = id>>9, g = (id>>6)&7, px = id&63
    float tv[2][8];
#pragma unroll
    for (int cc = 0; cc < 2; ++cc) {
        int id = tid + (cc << 9);
        int rq = id >> 9, g = (id >> 6) & 7, pxx = id & 63;
        const float* src = xf + (size_t)(g*8)*HWsz + (size_t)(h0 + rq)*W_ + w0 + pxx;
#pragma unroll
        for (int j = 0; j < 8; ++j) tv[cc][j] = src[(size_t)j*HWsz];
    }

    const int px = lane, gw = w0 + px;
    const int rowq = wv >> 2, tg = wv & 3;
    const int h = h0 + rowq;
    const int ka = 2*tg + (tg >> 1);        // tg 0..3 -> taps {0,1},{2,3},{5,6},{7,8}

    float pc[4];
#pragma unroll
    for (int ch = 0; ch < 4; ++ch) pc[ch] = xp[(size_t)ch*HWsz + (size_t)h*W_ + gw];

    f32x2 dd[4]; f32x2 mu;
#pragma unroll
    for (int i = 0; i < 2; ++i) {
        int k = ka + i;
        int r = k/3 - 1, d = k%3 - 1;
        int ih = h + r, iw = gw + d;
        bool ok = ((unsigned)ih < (unsigned)H_) && ((unsigned)iw < (unsigned)W_);
        int ihc = min(max(ih, 0), H_-1);
        int iwc = min(max(iw, 0), W_-1);
        mu[i] = ok ? (float)mk[(size_t)ihc*W_ + iwc] : 0.f;
#pragma unroll
        for (int ch = 0; ch < 4; ++ch) {
            float p = xp[(size_t)ch*HWsz + (size_t)ihc*W_ + iwc];
            dd[ch][i] = (ok ? p : 0.f) - pc[ch];   // reference zero-pads pn
        }
    }

    const f32x4* Wf4 = (const f32x4*)Wfold;
    const f32x2 z2 = {0.f, 0.f};
    f32x2 lg = z2;
#pragma unroll 8
    for (int c = 0; c < CIN; ++c) {
        f32x4 wa = Wf4[2*c];        // wave-uniform s_load
        f32x4 wb = Wf4[2*c + 1];
        f32x2 v = {wb[0], wb[0]};
        v = dd[0]*wa[0] + v;          // packed f32x2 fma
        v = dd[1]*wa[1] + v;
        v = dd[2]*wa[2] + v;
        v = dd[3]*wa[3] + v;
        v = __builtin_elementwise_max(v, z2);
        lg = v*wb[1] + lg;
    }
    float b2v = b2p[0];
    sw[rowq][ka    ][px] = (lg[0] + b2v) * mu[0];
    sw[rowq][ka + 1][px] = (lg[1] + b2v) * mu[1];

    // --- pack + store xg (coalesced 16B/lane, 1KB segments) ---
#pragma unroll
    for (int cc = 0; cc < 2; ++cc) {
        int id = tid + (cc << 9);
        int rq = id >> 9, g = (id >> 6) & 7, pxx = id & 63;
        uint4 q;
        q.x = pack2bf(tv[cc][0], tv[cc][1]); q.y = pack2bf(tv[cc][2], tv[cc][3]);
        q.z = pack2bf(tv[cc][4], tv[cc][5]); q.w = pack2bf(tv[cc][6], tv[cc][7]);
        *(uint4*)(xg + ((((size_t)(b*H_ + h0 + rq)*8 + g)*W_) + w0 + pxx)*8) = q;
    }
    __syncthreads();

    // softmax over 9 taps (128 threads) -> global sws
    if (tid < 128) {
        int rq = tid >> 6, p2 = tid & 63;
        float mu4 = (float)mk[(size_t)(h0 + rq)*W_ + w0 + p2];
        float lgv[9];
#pragma unroll
        for (int k = 0; k < 9; ++k) if (k != 4) lgv[k] = sw[rq][k][p2];
        lgv[4] = (Wfold[512] + b2v) * mu4;
        float mx = -1e30f;
#pragma unroll
        for (int k = 0; k < 9; ++k) mx = fmaxf(mx, lgv[k]);
        float s = 0.f, e[9];
#pragma unroll
        for (int k = 0; k < 9; ++k) { e[k] = __expf(lgv[k] - mx); s += e[k]; }
        float inv = 1.f / s;
        float* dst = sws + ((size_t)(b*H_ + h0 + rq)*9)*W_ + w0 + p2;
#pragma unroll
        for (int k = 0; k < 9; ++k) dst[(size_t)k*W_] = e[k] * inv;
    }
}

// ---------------- agg_k: async-stage xg -> weighted MFMA -> BN2 epilogue ----------------
// Block 256 thr (4 waves). Interior staging = 32 global_load_lds (1KB, zero VGPR).
// Phase C = R3's proven spill-free structure: aw[4] per k9 (no ping-pong),
// fin[2], swr[2][9] register prefetch. VGPR ~52.
__global__ __launch_bounds__(256, 4) void agg_k(
    const unsigned short* __restrict__ xg, const float* __restrict__ sws,
    const unsigned short* __restrict__ BwS,
    const float* __restrict__ g2, const float* __restrict__ bb2,
    const float* __restrict__ m2, const float* __restrict__ v2,
    float* __restrict__ out)
{
    __shared__ __align__(16) unsigned short fe[4][8][66][8];   // 33,792 B
    __shared__ __align__(16) float sbn[2][64];                 //    512 B

    const int tid = threadIdx.x;
    const int bx = blockIdx.x, by = blockIdx.y;
    const int b = by >> 5, h0 = (by & 31) << 1;
    const int w0 = bx << 6;
    const int lane = tid & 63, wv = tid >> 6;

    // --- interior staging: async, 8 (r,g) tasks per wave, 1KB each ---
#pragma unroll
    for (int it = 0; it < 8; ++it) {
        int u = it*4 + wv;                  // wave-uniform
        int g = u & 7, r = u >> 3;
        int gr = h0 - 1 + r;
        if ((unsigned)gr < (unsigned)H_) {
            const unsigned short* src =
                xg + ((((size_t)(b*H_ + gr)*8 + g)*W_) + w0 + lane)*8;
            gl_lds16(src, &fe[r][g][1][0]);
        } else {
            uint4 z = {0u, 0u, 0u, 0u};
            *(uint4*)&fe[r][g][1 + lane][0] = z;
        }
    }
    // --- halo: 64 tasks (2 cols x 8 g x 4 r), 16B each ---
    if (tid < 64) {
        int c2 = tid & 1, g = (tid >> 1) & 7, r = tid >> 4;
        int gr = h0 - 1 + r, gc = w0 - 1 + c2*65;
        uint4 q = {0u, 0u, 0u, 0u};
        if (((unsigned)gr < (unsigned)H_) && ((unsigned)gc < (unsigned)W_))
            q = *(const uint4*)(xg + ((((size_t)(b*H_ + gr)*8 + g)*W_) + gc)*8);
        *(uint4*)&fe[r][g][c2*65][0] = q;
    }
    // BN2 table: tid in [64,128)
    if (tid >= 64 && tid < 128) {
        int o = tid - 64;
        float sc = g2[o] * rsqrtf(v2[o] + 1e-5f);
        sbn[0][o] = sc;
        sbn[1][o] = bb2[o] - m2[o]*sc;
    }

    // prefetch softmax weights for this wave (both halves, 9 taps) - registers
    const int nt = wv & 1, rh = wv >> 1;
    const int l31 = lane & 31, l5 = lane >> 5;
    const int hC = h0 + rh;
    const float* swp = sws + ((size_t)(b*H_ + hC)*9)*W_ + w0 + l31;
    float swr[2][9];
#pragma unroll
    for (int half = 0; half < 2; ++half)
#pragma unroll
        for (int k9 = 0; k9 < 9; ++k9)
            swr[half][k9] = swp[(size_t)k9*W_ + half*32];

    __syncthreads();

    // --- MFMA: A=Wagg fragments (L2), B=feats (LDS) ---
    const f32x16 fz16 = {0.f,0.f,0.f,0.f,0.f,0.f,0.f,0.f,0.f,0.f,0.f,0.f,0.f,0.f,0.f,0.f};
    f32x16 fin[2] = {fz16, fz16};

#pragma unroll
    for (int k9 = 0; k9 < 9; ++k9) {
        const int rr = rh + k9/3;            // fe row (fe[0] = global row h0-1)
        const int dwp = k9 % 3;

        s16x8 aw[4];
#pragma unroll
        for (int ks = 0; ks < 4; ++ks)
            aw[ks] = *(const s16x8*)(BwS + (size_t)((((k9<<2) + ks)*2 + nt) << 9) + lane*8);

#pragma unroll
        for (int half = 0; half < 2; ++half) {
            int col = half*32 + l31 + dwp;   // 1 + px + (dwp-1)
            f32x16 tmp = fz16;
#pragma unroll
            for (int ks = 0; ks < 4; ++ks) {
                s16x8 bfr = *(const s16x8*)&fe[rr][ks*2 + l5][col][0];
                tmp = __builtin_amdgcn_mfma_f32_32x32x16_bf16(aw[ks], bfr, tmp, 0, 0, 0);
            }
            float wsc = swr[half][k9];
#pragma unroll
            for (int c = 0; c < 16; ++c) fin[half][c] += wsc * tmp[c];
        }
    }

    // --- epilogue: BN2 + ReLU, coalesced dword stores (128B segments) ---
    int obase = nt*32 + 4*l5;
#pragma unroll
    for (int half = 0; half < 2; ++half) {
        float* od = out + (((size_t)b*COUT + obase)*H_ + hC)*W_ + w0 + half*32 + l31;
#pragma unroll
        for (int v = 0; v < 4; ++v) {
            f32x4 sc4 = *(const f32x4*)&sbn[0][obase + 8*v];
            f32x4 tc4 = *(const f32x4*)&sbn[1][obase + 8*v];
#pragma unroll
            for (int c = 0; c < 4; ++c)
                od[(size_t)(8*v + c)*HWsz] =
                    fmaxf(fmaf(fin[half][4*v + c], sc4[c], tc4[c]), 0.f);
        }
    }
}

extern "C" void kernel_launch(void* const* d_in, const int* in_sizes, int n_in,
                              void* d_out, int out_size, void* d_ws, size_t ws_size,
                              hipStream_t stream)
{
    const float* x    = (const float*)d_in[0];
    const int*   mask = (const int*)d_in[1];
    const float* W1   = (const float*)d_in[2];
    const float* g1   = (const float*)d_in[3];
    const float* b1   = (const float*)d_in[4];
    const float* m1   = (const float*)d_in[5];
    const float* v1   = (const float*)d_in[6];
    const float* W2   = (const float*)d_in[7];
    const float* b2   = (const float*)d_in[8];
    const float* Wagg = (const float*)d_in[9];
    const float* g2   = (const float*)d_in[10];
    const float* bb2  = (const float*)d_in[11];
    const float* m2   = (const float*)d_in[12];
    const float* v2   = (const float*)d_in[13];
    float* outp = (float*)d_out;

    char* ws = (char*)d_ws;
    unsigned short* BwS   = (unsigned short*)(ws + 0);       // 73,728 B
    float*          Wfold = (float*)(ws + 73728);            //  2,052 B
    float*          sws   = (float*)(ws + 76800);            // 9,437,184 B
    unsigned short* xg    = (unsigned short*)(ws + 9513984); // 33,554,432 B

    hipLaunchKernelGGL(prep_bw, dim3(18), dim3(256), 0, stream,
                       Wagg, W1, g1, b1, m1, v1, W2, BwS, Wfold);
    hipLaunchKernelGGL(sw_k, dim3(W_/64, 64), dim3(512), 0, stream,
                       x, mask, Wfold, b2, sws, xg);
    hipLaunchKernelGGL(agg_k, dim3(W_/64, 64), dim3(256), 0, stream,
                       xg, sws, BwS, g2, bb2, m2, v2, outp);
}